// Round 4
// baseline (1215.034 us; speedup 1.0000x reference)
//
#include <hip/hip_runtime.h>

#define NN 50000
#define NR 4
#define NE 800000
#define DD 128
#define NSEG (NR * NN)                       // 200000 segments
#define SCHUNK 1024
#define NCHUNK ((NSEG + SCHUNK - 1) / SCHUNK)  // 196

// ---------------------------------------------------------------------------
// rel_w = softmax(features @ Wrw + brw)   [NN, 4]
// ---------------------------------------------------------------------------
__global__ __launch_bounds__(256) void relw_kernel(
    const float* __restrict__ feat, const float* __restrict__ Wrw,
    const float* __restrict__ brw, float* __restrict__ relw) {
  int wave = threadIdx.x >> 6, lane = threadIdx.x & 63;
  int n = blockIdx.x * 4 + wave;
  if (n >= NN) return;
  float2 f = reinterpret_cast<const float2*>(feat + (size_t)n * DD)[lane];
  float4 w0 = reinterpret_cast<const float4*>(Wrw)[2 * lane];
  float4 w1 = reinterpret_cast<const float4*>(Wrw)[2 * lane + 1];
  float a0 = f.x * w0.x + f.y * w1.x;
  float a1 = f.x * w0.y + f.y * w1.y;
  float a2 = f.x * w0.z + f.y * w1.z;
  float a3 = f.x * w0.w + f.y * w1.w;
  for (int off = 32; off; off >>= 1) {
    a0 += __shfl_xor(a0, off);
    a1 += __shfl_xor(a1, off);
    a2 += __shfl_xor(a2, off);
    a3 += __shfl_xor(a3, off);
  }
  if (lane == 0) {
    a0 += brw[0]; a1 += brw[1]; a2 += brw[2]; a3 += brw[3];
    float m = fmaxf(fmaxf(a0, a1), fmaxf(a2, a3));
    float e0 = __expf(a0 - m), e1 = __expf(a1 - m);
    float e2 = __expf(a2 - m), e3 = __expf(a3 - m);
    float inv = 1.f / (e0 + e1 + e2 + e3);
    reinterpret_cast<float4*>(relw)[n] =
        make_float4(e0 * inv, e1 * inv, e2 * inv, e3 * inv);
  }
}

// ---------------------------------------------------------------------------
// count: cnt[r*NN + dst]++ over all 3.2M edges (int atomics)
// ---------------------------------------------------------------------------
__global__ __launch_bounds__(256) void count_kernel(
    const int* __restrict__ eidx, int* __restrict__ cnt) {
  int idx = blockIdx.x * 256 + threadIdx.x;
  if (idx >= NR * NE) return;
  int r = idx / NE, e = idx - r * NE;
  int dst = eidx[(size_t)r * 2 * NE + NE + e];
  atomicAdd(&cnt[r * NN + dst], 1);
}

// ---------------------------------------------------------------------------
// 3-kernel exclusive scan over cnt[NSEG] -> off[NSEG]; off_run = copy
// ---------------------------------------------------------------------------
__global__ __launch_bounds__(256) void scan_local(
    const int* __restrict__ cnt, int* __restrict__ off,
    int* __restrict__ partial) {
  __shared__ int lds[256];
  int base = blockIdx.x * SCHUNK, t = threadIdx.x;
  int v[4], s = 0;
#pragma unroll
  for (int j = 0; j < 4; ++j) {
    int i = base + t * 4 + j;
    v[j] = (i < NSEG) ? cnt[i] : 0;
    s += v[j];
  }
  lds[t] = s;
  __syncthreads();
  for (int d = 1; d < 256; d <<= 1) {
    int x = (t >= d) ? lds[t - d] : 0;
    __syncthreads();
    lds[t] += x;
    __syncthreads();
  }
  int excl = (t == 0) ? 0 : lds[t - 1];
  if (t == 255) partial[blockIdx.x] = lds[255];
#pragma unroll
  for (int j = 0; j < 4; ++j) {
    int i = base + t * 4 + j;
    if (i < NSEG) off[i] = excl;
    excl += v[j];
  }
}

__global__ __launch_bounds__(256) void scan_partials(int* __restrict__ partial) {
  __shared__ int lds[256];
  int t = threadIdx.x;
  int v = (t < NCHUNK) ? partial[t] : 0;
  lds[t] = v;
  __syncthreads();
  for (int d = 1; d < 256; d <<= 1) {
    int x = (t >= d) ? lds[t - d] : 0;
    __syncthreads();
    lds[t] += x;
    __syncthreads();
  }
  int excl = (t == 0) ? 0 : lds[t - 1];
  if (t < NCHUNK) partial[t] = excl;
}

__global__ __launch_bounds__(256) void scan_add(
    int* __restrict__ off, const int* __restrict__ partial,
    int* __restrict__ off_run) {
  int base = blockIdx.x * SCHUNK;
  int add = partial[blockIdx.x];
  for (int j = threadIdx.x; j < SCHUNK; j += 256) {
    int i = base + j;
    if (i < NSEG) {
      int o = off[i] + add;
      off[i] = o;
      off_run[i] = o;
    }
  }
}

// ---------------------------------------------------------------------------
// place: s_rec[pos] = (src, w) packed int2, pos = off_run[seg]++
// single 8B random write per edge (was 2x 4B to separate arrays)
// ---------------------------------------------------------------------------
__global__ __launch_bounds__(256) void place_kernel(
    const int* __restrict__ eidx, const float* __restrict__ ew,
    int* __restrict__ off_run, int2* __restrict__ s_rec) {
  int idx = blockIdx.x * 256 + threadIdx.x;
  if (idx >= NR * NE) return;
  int r = idx / NE, e = idx - r * NE;
  int src = eidx[(size_t)r * 2 * NE + e];
  int dst = eidx[(size_t)r * 2 * NE + NE + e];
  float w = ew[(size_t)r * NE + e];
  int pos = atomicAdd(&off_run[r * NN + dst], 1);
  s_rec[pos] = make_int2(src, __float_as_int(w));
}

// ---------------------------------------------------------------------------
// node_kernel: fully fused gather + combine + gate.
// 512 threads = 8 waves; each wave owns 4 nodes end-to-end; 32 nodes/block.
// Per relation r: stage Wr[r] (64KB) in LDS; per node: gather CSR segment
// into registers (h = float2/lane, pre-scaled by rel_w), matvec h @ W via
// __shfl broadcast, accumulate y. Finally gate with Wg staged in LDS.
// H is never materialized; out written exactly once.
// ---------------------------------------------------------------------------
__global__ __launch_bounds__(512, 4) void node_kernel(
    const float* __restrict__ feat, const int2* __restrict__ s_rec,
    const int* __restrict__ off, const int* __restrict__ cnt,
    const float* __restrict__ relw, const float* __restrict__ Wr,
    const float* __restrict__ br, const float* __restrict__ Wg,
    const float* __restrict__ bg, float* __restrict__ out) {
  __shared__ float wlds[DD * DD];  // 64 KB
  int wave = threadIdx.x >> 6, lane = threadIdx.x & 63;
  int nbase = blockIdx.x * 32 + wave * 4;

  float2 y[4];
#pragma unroll
  for (int j = 0; j < 4; ++j) y[j] = make_float2(0.f, 0.f);

  for (int r = 0; r < NR; ++r) {
    __syncthreads();  // protect wlds readers of previous relation
    {
      const float* W = Wr + (size_t)r * DD * DD;
      for (int i = threadIdx.x; i < DD * DD / 4; i += 512)
        reinterpret_cast<float4*>(wlds)[i] =
            reinterpret_cast<const float4*>(W)[i];
    }
    __syncthreads();
    float2 bv = reinterpret_cast<const float2*>(br + (size_t)r * DD)[lane];
#pragma unroll
    for (int nl = 0; nl < 4; ++nl) {
      int n = nbase + nl;
      if (n >= NN) continue;  // wave-uniform
      int seg = r * NN + n;
      int start = off[seg], deg = cnt[seg];
      // ---- gather: h = sum_e w_e * feat[src_e], 4 rows in flight ----
      float ax = 0.f, ay = 0.f, bx = 0.f, by = 0.f, sw = 0.f;
      int i = 0;
      for (; i + 4 <= deg; i += 4) {
        int2 e0 = s_rec[start + i], e1 = s_rec[start + i + 1];
        int2 e2 = s_rec[start + i + 2], e3 = s_rec[start + i + 3];
        float w0 = __int_as_float(e0.y), w1 = __int_as_float(e1.y);
        float w2 = __int_as_float(e2.y), w3 = __int_as_float(e3.y);
        float2 f0 = reinterpret_cast<const float2*>(feat + (size_t)e0.x * DD)[lane];
        float2 f1 = reinterpret_cast<const float2*>(feat + (size_t)e1.x * DD)[lane];
        float2 f2 = reinterpret_cast<const float2*>(feat + (size_t)e2.x * DD)[lane];
        float2 f3 = reinterpret_cast<const float2*>(feat + (size_t)e3.x * DD)[lane];
        ax += w0 * f0.x + w2 * f2.x;
        ay += w0 * f0.y + w2 * f2.y;
        bx += w1 * f1.x + w3 * f3.x;
        by += w1 * f1.y + w3 * f3.y;
        sw += (w0 + w1) + (w2 + w3);
      }
      for (; i < deg; ++i) {
        int2 e0 = s_rec[start + i];
        float w0 = __int_as_float(e0.y);
        float2 f0 = reinterpret_cast<const float2*>(feat + (size_t)e0.x * DD)[lane];
        ax += w0 * f0.x;
        ay += w0 * f0.y;
        sw += w0;
      }
      float rw = relw[n * 4 + r];
      float hx = rw * (ax + bx), hy = rw * (ay + by);  // pre-scaled h[2l],h[2l+1]
      // ---- matvec: acc[j] = sum_k h[k] * W[k][j], j = 2*lane, 2*lane+1 ----
      float sb = rw * sw;
      float2 acc = make_float2(sb * bv.x, sb * bv.y);
      const float2* w2p = reinterpret_cast<const float2*>(wlds);
#pragma unroll 16
      for (int k = 0; k < 64; ++k) {
        float ha = __shfl(hx, k);  // h[2k]
        float hb = __shfl(hy, k);  // h[2k+1]
        float2 wv0 = w2p[k * DD + lane];        // W[2k][2l..2l+1]
        float2 wv1 = w2p[k * DD + 64 + lane];   // W[2k+1][2l..2l+1]
        acc.x += ha * wv0.x + hb * wv1.x;
        acc.y += ha * wv0.y + hb * wv1.y;
      }
      y[nl].x += acc.x;
      y[nl].y += acc.y;
    }
  }

  // ---- gate: g = y @ Wg + bg; out = sigmoid(g) * y ----
  __syncthreads();
  for (int i = threadIdx.x; i < DD * DD / 4; i += 512)
    reinterpret_cast<float4*>(wlds)[i] = reinterpret_cast<const float4*>(Wg)[i];
  __syncthreads();
  float2 gbv = reinterpret_cast<const float2*>(bg)[lane];
  const float2* w2p = reinterpret_cast<const float2*>(wlds);
#pragma unroll
  for (int nl = 0; nl < 4; ++nl) {
    int n = nbase + nl;
    if (n >= NN) continue;
    float cx = y[nl].x, cy = y[nl].y;
    float2 acc = gbv;
#pragma unroll 16
    for (int k = 0; k < 64; ++k) {
      float ha = __shfl(cx, k);
      float hb = __shfl(cy, k);
      float2 wv0 = w2p[k * DD + lane];
      float2 wv1 = w2p[k * DD + 64 + lane];
      acc.x += ha * wv0.x + hb * wv1.x;
      acc.y += ha * wv0.y + hb * wv1.y;
    }
    float2 res;
    res.x = cx / (1.f + __expf(-acc.x));
    res.y = cy / (1.f + __expf(-acc.y));
    reinterpret_cast<float2*>(out + (size_t)n * DD)[lane] = res;
  }
}

// ---------------------------------------------------------------------------
extern "C" void kernel_launch(void* const* d_in, const int* in_sizes, int n_in,
                              void* d_out, int out_size, void* d_ws,
                              size_t ws_size, hipStream_t stream) {
  const float* feat = (const float*)d_in[0];
  const int* eidx   = (const int*)d_in[1];   // [4][2][800000] int32
  const float* ew   = (const float*)d_in[2];
  const float* Wr   = (const float*)d_in[3];
  const float* br   = (const float*)d_in[4];
  const float* Wrw  = (const float*)d_in[5];
  const float* brw  = (const float*)d_in[6];
  const float* Wg   = (const float*)d_in[7];
  const float* bg   = (const float*)d_in[8];
  float* out = (float*)d_out;

  // ws layout (~29 MB): s_rec | cnt | off | offrun | part | relw
  char* p = (char*)d_ws;
  int2*  s_rec  = (int2*)p;   p += (size_t)NR * NE * 8;   // 25.6 MB
  int*   cnt    = (int*)p;    p += (size_t)NSEG * 4;
  int*   off    = (int*)p;    p += (size_t)NSEG * 4;
  int*   offrun = (int*)p;    p += (size_t)NSEG * 4;
  int*   part   = (int*)p;    p += 1024;
  float* relw   = (float*)p;  p += (size_t)NN * NR * 4;

  hipMemsetAsync(cnt, 0, (size_t)NSEG * 4, stream);

  relw_kernel<<<(NN + 3) / 4, 256, 0, stream>>>(feat, Wrw, brw, relw);
  count_kernel<<<(NR * NE + 255) / 256, 256, 0, stream>>>(eidx, cnt);
  scan_local<<<NCHUNK, 256, 0, stream>>>(cnt, off, part);
  scan_partials<<<1, 256, 0, stream>>>(part);
  scan_add<<<NCHUNK, 256, 0, stream>>>(off, part, offrun);
  place_kernel<<<(NR * NE + 255) / 256, 256, 0, stream>>>(eidx, ew, offrun,
                                                          s_rec);
  node_kernel<<<(NN + 31) / 32, 512, 0, stream>>>(feat, s_rec, off, cnt, relw,
                                                  Wr, br, Wg, bg, out);
}

// Round 5
// 970.308 us; speedup vs baseline: 1.2522x; 1.2522x over previous
//
#include <hip/hip_runtime.h>
#include <hip/hip_fp16.h>

#define NN 50000
#define NR 4
#define NE 800000
#define DD 128
#define NSEG (NR * NN)                       // 200000 segments
#define SCHUNK 1024
#define NCHUNK ((NSEG + SCHUNK - 1) / SCHUNK)  // 196

// ---------------------------------------------------------------------------
// rel_w = softmax(features @ Wrw + brw)   [NN, 4]
// ---------------------------------------------------------------------------
__global__ __launch_bounds__(256) void relw_kernel(
    const float* __restrict__ feat, const float* __restrict__ Wrw,
    const float* __restrict__ brw, float* __restrict__ relw) {
  int wave = threadIdx.x >> 6, lane = threadIdx.x & 63;
  int n = blockIdx.x * 4 + wave;
  if (n >= NN) return;
  float2 f = reinterpret_cast<const float2*>(feat + (size_t)n * DD)[lane];
  float4 w0 = reinterpret_cast<const float4*>(Wrw)[2 * lane];
  float4 w1 = reinterpret_cast<const float4*>(Wrw)[2 * lane + 1];
  float a0 = f.x * w0.x + f.y * w1.x;
  float a1 = f.x * w0.y + f.y * w1.y;
  float a2 = f.x * w0.z + f.y * w1.z;
  float a3 = f.x * w0.w + f.y * w1.w;
  for (int off = 32; off; off >>= 1) {
    a0 += __shfl_xor(a0, off);
    a1 += __shfl_xor(a1, off);
    a2 += __shfl_xor(a2, off);
    a3 += __shfl_xor(a3, off);
  }
  if (lane == 0) {
    a0 += brw[0]; a1 += brw[1]; a2 += brw[2]; a3 += brw[3];
    float m = fmaxf(fmaxf(a0, a1), fmaxf(a2, a3));
    float e0 = __expf(a0 - m), e1 = __expf(a1 - m);
    float e2 = __expf(a2 - m), e3 = __expf(a3 - m);
    float inv = 1.f / (e0 + e1 + e2 + e3);
    reinterpret_cast<float4*>(relw)[n] =
        make_float4(e0 * inv, e1 * inv, e2 * inv, e3 * inv);
  }
}

// ---------------------------------------------------------------------------
// count: cnt[r*NN + dst]++ over all 3.2M edges
// ---------------------------------------------------------------------------
__global__ __launch_bounds__(256) void count_kernel(
    const int* __restrict__ eidx, int* __restrict__ cnt) {
  int idx = blockIdx.x * 256 + threadIdx.x;
  if (idx >= NR * NE) return;
  int r = idx / NE, e = idx - r * NE;
  int dst = eidx[(size_t)r * 2 * NE + NE + e];
  atomicAdd(&cnt[r * NN + dst], 1);
}

// ---------------------------------------------------------------------------
// 3-kernel exclusive scan over cnt[NSEG] -> off[NSEG]; off_run = copy
// ---------------------------------------------------------------------------
__global__ __launch_bounds__(256) void scan_local(
    const int* __restrict__ cnt, int* __restrict__ off,
    int* __restrict__ partial) {
  __shared__ int lds[256];
  int base = blockIdx.x * SCHUNK, t = threadIdx.x;
  int v[4], s = 0;
#pragma unroll
  for (int j = 0; j < 4; ++j) {
    int i = base + t * 4 + j;
    v[j] = (i < NSEG) ? cnt[i] : 0;
    s += v[j];
  }
  lds[t] = s;
  __syncthreads();
  for (int d = 1; d < 256; d <<= 1) {
    int x = (t >= d) ? lds[t - d] : 0;
    __syncthreads();
    lds[t] += x;
    __syncthreads();
  }
  int excl = (t == 0) ? 0 : lds[t - 1];
  if (t == 255) partial[blockIdx.x] = lds[255];
#pragma unroll
  for (int j = 0; j < 4; ++j) {
    int i = base + t * 4 + j;
    if (i < NSEG) off[i] = excl;
    excl += v[j];
  }
}

__global__ __launch_bounds__(256) void scan_partials(int* __restrict__ partial) {
  __shared__ int lds[256];
  int t = threadIdx.x;
  int v = (t < NCHUNK) ? partial[t] : 0;
  lds[t] = v;
  __syncthreads();
  for (int d = 1; d < 256; d <<= 1) {
    int x = (t >= d) ? lds[t - d] : 0;
    __syncthreads();
    lds[t] += x;
    __syncthreads();
  }
  int excl = (t == 0) ? 0 : lds[t - 1];
  if (t < NCHUNK) partial[t] = excl;
}

__global__ __launch_bounds__(256) void scan_add(
    int* __restrict__ off, const int* __restrict__ partial,
    int* __restrict__ off_run) {
  int base = blockIdx.x * SCHUNK;
  int add = partial[blockIdx.x];
  for (int j = threadIdx.x; j < SCHUNK; j += 256) {
    int i = base + j;
    if (i < NSEG) {
      int o = off[i] + add;
      off[i] = o;
      off_run[i] = o;
    }
  }
}

// ---------------------------------------------------------------------------
// place: s_eid[pos] = e (4B random write; src/w re-read at gather)
// ---------------------------------------------------------------------------
__global__ __launch_bounds__(256) void place_kernel(
    const int* __restrict__ eidx, int* __restrict__ off_run,
    int* __restrict__ s_eid) {
  int idx = blockIdx.x * 256 + threadIdx.x;
  if (idx >= NR * NE) return;
  int r = idx / NE, e = idx - r * NE;
  int dst = eidx[(size_t)r * 2 * NE + NE + e];
  int pos = atomicAdd(&off_run[r * NN + dst], 1);
  s_eid[pos] = e;
}

// ---------------------------------------------------------------------------
// m_kernel: M_r = F @ Wr[r]  in fp16.  blockIdx.y = r.
// 256 thr, 32 nodes/block; Wr (64KB) in LDS, F rows staged (4KB).
// ---------------------------------------------------------------------------
__global__ __launch_bounds__(256) void m_kernel(
    const float* __restrict__ feat, const float* __restrict__ Wr,
    __half* __restrict__ M) {
  __shared__ float wlds[DD * DD];   // 64 KB
  __shared__ float flds[8][DD];     // 4 KB
  int r = blockIdx.y;
  const float* W = Wr + (size_t)r * DD * DD;
  for (int i = threadIdx.x; i < DD * DD / 4; i += 256)
    reinterpret_cast<float4*>(wlds)[i] = reinterpret_cast<const float4*>(W)[i];
  int dgrp = threadIdx.x & 31, nl = threadIdx.x >> 5;
  int nbase = blockIdx.x * 32;
  for (int s = 0; s < 4; ++s) {
    int n0 = nbase + s * 8;
    __syncthreads();
    {
      int n = n0 + nl;
      float4 fv = make_float4(0.f, 0.f, 0.f, 0.f);
      if (n < NN) fv = reinterpret_cast<const float4*>(feat + (size_t)n * DD)[dgrp];
      reinterpret_cast<float4*>(&flds[nl][0])[dgrp] = fv;
    }
    __syncthreads();
    int n = n0 + nl;
    float4 acc = make_float4(0.f, 0.f, 0.f, 0.f);
#pragma unroll 8
    for (int k = 0; k < DD; ++k) {
      float f = flds[nl][k];
      float4 wv = reinterpret_cast<const float4*>(&wlds[k * DD])[dgrp];
      acc.x += f * wv.x; acc.y += f * wv.y;
      acc.z += f * wv.z; acc.w += f * wv.w;
    }
    if (n < NN) {
      __half2 h01 = __floats2half2_rn(acc.x, acc.y);
      __half2 h23 = __floats2half2_rn(acc.z, acc.w);
      __half2* mp = reinterpret_cast<__half2*>(
          M + ((size_t)r * NN + n) * DD + 4 * dgrp);
      mp[0] = h01;
      mp[1] = h23;
    }
  }
}

// ---------------------------------------------------------------------------
// gather_y: one wave per node, zero LDS, max occupancy.
// y[n] = sum_r rw[n,r] * ( sum_e w_e * M_r[src_e]  +  (sum_e w_e) * br[r] )
// 8-edge batches: lanes 0..7 load metadata (eid -> src,w), __shfl broadcast,
// 8 independent 256B M-row loads in flight.
// ---------------------------------------------------------------------------
__global__ __launch_bounds__(256) void gather_y(
    const __half* __restrict__ M, const int* __restrict__ s_eid,
    const int* __restrict__ off, const int* __restrict__ cnt,
    const int* __restrict__ eidx, const float* __restrict__ ew,
    const float* __restrict__ relw, const float* __restrict__ br,
    float* __restrict__ y) {
  int wave = threadIdx.x >> 6, lane = threadIdx.x & 63;
  int n = blockIdx.x * 4 + wave;
  if (n >= NN) return;
  float4 rw4 = reinterpret_cast<const float4*>(relw)[n];
  float rwv[4] = {rw4.x, rw4.y, rw4.z, rw4.w};
  float2 acc = make_float2(0.f, 0.f);
#pragma unroll
  for (int r = 0; r < NR; ++r) {
    int seg = r * NN + n;
    int start = off[seg], deg = cnt[seg];
    const int* srcbase = eidx + (size_t)r * 2 * NE;
    const float* wbase = ew + (size_t)r * NE;
    const __half2* mbase =
        reinterpret_cast<const __half2*>(M + (size_t)r * NN * DD);
    float2 pacc = make_float2(0.f, 0.f);
    float sw = 0.f;
    for (int i = 0; i < deg; i += 8) {
      int nb = deg - i;
      nb = nb > 8 ? 8 : nb;
      int eid = 0;
      if (lane < nb) eid = s_eid[start + i + lane];
      int src_l = (lane < nb) ? srcbase[eid] : 0;
      float w_l = (lane < nb) ? wbase[eid] : 0.f;
      if (nb == 8) {
#pragma unroll
        for (int j = 0; j < 8; ++j) {
          int s = __shfl(src_l, j);
          float w = __shfl(w_l, j);
          float2 mf = __half22float2(mbase[(size_t)s * 64 + lane]);
          pacc.x += w * mf.x;
          pacc.y += w * mf.y;
          sw += w;
        }
      } else {
        for (int j = 0; j < nb; ++j) {
          int s = __shfl(src_l, j);
          float w = __shfl(w_l, j);
          float2 mf = __half22float2(mbase[(size_t)s * 64 + lane]);
          pacc.x += w * mf.x;
          pacc.y += w * mf.y;
          sw += w;
        }
      }
    }
    float2 bv = reinterpret_cast<const float2*>(br + (size_t)r * DD)[lane];
    float rw = rwv[r];
    acc.x += rw * (pacc.x + sw * bv.x);
    acc.y += rw * (pacc.y + sw * bv.y);
  }
  reinterpret_cast<float2*>(y + (size_t)n * DD)[lane] = acc;
}

// ---------------------------------------------------------------------------
// gate: out = sigmoid(out @ Wg + bg) * out, in place (out holds y)
// ---------------------------------------------------------------------------
__global__ __launch_bounds__(256) void gate_kernel(
    float* __restrict__ out, const float* __restrict__ Wg,
    const float* __restrict__ bg) {
  __shared__ float wlds[DD * DD];
  __shared__ float clds[8][DD];
  for (int i = threadIdx.x; i < DD * DD / 4; i += 256)
    reinterpret_cast<float4*>(wlds)[i] = reinterpret_cast<const float4*>(Wg)[i];
  int dgrp = threadIdx.x & 31, nl = threadIdx.x >> 5;
  float4 bv = reinterpret_cast<const float4*>(bg)[dgrp];
  int nbase = blockIdx.x * 32;
  for (int s = 0; s < 4; ++s) {
    int n0 = nbase + s * 8;
    __syncthreads();
    {
      int n = n0 + nl;
      float4 cv = make_float4(0.f, 0.f, 0.f, 0.f);
      if (n < NN) cv = reinterpret_cast<const float4*>(out + (size_t)n * DD)[dgrp];
      reinterpret_cast<float4*>(&clds[nl][0])[dgrp] = cv;
    }
    __syncthreads();
    int n = n0 + nl;
    float4 acc = bv;
#pragma unroll 8
    for (int k = 0; k < DD; ++k) {
      float c = clds[nl][k];
      float4 wv = reinterpret_cast<const float4*>(&wlds[k * DD])[dgrp];
      acc.x += c * wv.x; acc.y += c * wv.y;
      acc.z += c * wv.z; acc.w += c * wv.w;
    }
    if (n < NN) {
      float4 cv = reinterpret_cast<float4*>(&clds[nl][0])[dgrp];
      float4 res;
      res.x = cv.x / (1.f + __expf(-acc.x));
      res.y = cv.y / (1.f + __expf(-acc.y));
      res.z = cv.z / (1.f + __expf(-acc.z));
      res.w = cv.w / (1.f + __expf(-acc.w));
      reinterpret_cast<float4*>(out + (size_t)n * DD)[dgrp] = res;
    }
  }
}

// ---------------------------------------------------------------------------
extern "C" void kernel_launch(void* const* d_in, const int* in_sizes, int n_in,
                              void* d_out, int out_size, void* d_ws,
                              size_t ws_size, hipStream_t stream) {
  const float* feat = (const float*)d_in[0];
  const int* eidx   = (const int*)d_in[1];   // [4][2][800000] int32
  const float* ew   = (const float*)d_in[2];
  const float* Wr   = (const float*)d_in[3];
  const float* br   = (const float*)d_in[4];
  const float* Wrw  = (const float*)d_in[5];
  const float* brw  = (const float*)d_in[6];
  const float* Wg   = (const float*)d_in[7];
  const float* bg   = (const float*)d_in[8];
  float* out = (float*)d_out;

  // ws layout (~67.2 MB): s_eid | cnt | off | offrun | part | relw | M
  char* p = (char*)d_ws;
  int*    s_eid  = (int*)p;    p += (size_t)NR * NE * 4;       // 12.8 MB
  int*    cnt    = (int*)p;    p += (size_t)NSEG * 4;
  int*    off    = (int*)p;    p += (size_t)NSEG * 4;
  int*    offrun = (int*)p;    p += (size_t)NSEG * 4;
  int*    part   = (int*)p;    p += 4096;
  float*  relw   = (float*)p;  p += (size_t)NN * NR * 4;
  __half* M      = (__half*)p; p += (size_t)NR * NN * DD * 2;  // 51.2 MB

  hipMemsetAsync(cnt, 0, (size_t)NSEG * 4, stream);

  relw_kernel<<<(NN + 3) / 4, 256, 0, stream>>>(feat, Wrw, brw, relw);
  count_kernel<<<(NR * NE + 255) / 256, 256, 0, stream>>>(eidx, cnt);
  scan_local<<<NCHUNK, 256, 0, stream>>>(cnt, off, part);
  scan_partials<<<1, 256, 0, stream>>>(part);
  scan_add<<<NCHUNK, 256, 0, stream>>>(off, part, offrun);
  place_kernel<<<(NR * NE + 255) / 256, 256, 0, stream>>>(eidx, offrun, s_eid);
  m_kernel<<<dim3((NN + 31) / 32, NR), 256, 0, stream>>>(feat, Wr, M);
  gather_y<<<(NN + 3) / 4, 256, 0, stream>>>(M, s_eid, off, cnt, eidx, ew,
                                             relw, br, out);
  gate_kernel<<<(NN + 31) / 32, 256, 0, stream>>>(out, Wg, bg);
}

// Round 6
// 886.508 us; speedup vs baseline: 1.3706x; 1.0945x over previous
//
#include <hip/hip_runtime.h>
#include <hip/hip_fp16.h>

#define NN 50000
#define NR 4
#define NE 800000
#define DD 128
#define NSEG (NR * NN)                       // 200000 segments
#define SCHUNK 1024
#define NCHUNK ((NSEG + SCHUNK - 1) / SCHUNK)  // 196

// ---------------------------------------------------------------------------
// rel_w = softmax(features @ Wrw + brw)   [NN, 4]
// ---------------------------------------------------------------------------
__global__ __launch_bounds__(256) void relw_kernel(
    const float* __restrict__ feat, const float* __restrict__ Wrw,
    const float* __restrict__ brw, float* __restrict__ relw) {
  int wave = threadIdx.x >> 6, lane = threadIdx.x & 63;
  int n = blockIdx.x * 4 + wave;
  if (n >= NN) return;
  float2 f = reinterpret_cast<const float2*>(feat + (size_t)n * DD)[lane];
  float4 w0 = reinterpret_cast<const float4*>(Wrw)[2 * lane];
  float4 w1 = reinterpret_cast<const float4*>(Wrw)[2 * lane + 1];
  float a0 = f.x * w0.x + f.y * w1.x;
  float a1 = f.x * w0.y + f.y * w1.y;
  float a2 = f.x * w0.z + f.y * w1.z;
  float a3 = f.x * w0.w + f.y * w1.w;
  for (int off = 32; off; off >>= 1) {
    a0 += __shfl_xor(a0, off);
    a1 += __shfl_xor(a1, off);
    a2 += __shfl_xor(a2, off);
    a3 += __shfl_xor(a3, off);
  }
  if (lane == 0) {
    a0 += brw[0]; a1 += brw[1]; a2 += brw[2]; a3 += brw[3];
    float m = fmaxf(fmaxf(a0, a1), fmaxf(a2, a3));
    float e0 = __expf(a0 - m), e1 = __expf(a1 - m);
    float e2 = __expf(a2 - m), e3 = __expf(a3 - m);
    float inv = 1.f / (e0 + e1 + e2 + e3);
    reinterpret_cast<float4*>(relw)[n] =
        make_float4(e0 * inv, e1 * inv, e2 * inv, e3 * inv);
  }
}

// ---------------------------------------------------------------------------
// count: cnt[r*NN + dst]++ over all 3.2M edges
// ---------------------------------------------------------------------------
__global__ __launch_bounds__(256) void count_kernel(
    const int* __restrict__ eidx, int* __restrict__ cnt) {
  int idx = blockIdx.x * 256 + threadIdx.x;
  if (idx >= NR * NE) return;
  int r = idx / NE, e = idx - r * NE;
  int dst = eidx[(size_t)r * 2 * NE + NE + e];
  atomicAdd(&cnt[r * NN + dst], 1);
}

// ---------------------------------------------------------------------------
// 3-kernel exclusive scan over cnt[NSEG] -> off[NSEG]; off_run = copy
// ---------------------------------------------------------------------------
__global__ __launch_bounds__(256) void scan_local(
    const int* __restrict__ cnt, int* __restrict__ off,
    int* __restrict__ partial) {
  __shared__ int lds[256];
  int base = blockIdx.x * SCHUNK, t = threadIdx.x;
  int v[4], s = 0;
#pragma unroll
  for (int j = 0; j < 4; ++j) {
    int i = base + t * 4 + j;
    v[j] = (i < NSEG) ? cnt[i] : 0;
    s += v[j];
  }
  lds[t] = s;
  __syncthreads();
  for (int d = 1; d < 256; d <<= 1) {
    int x = (t >= d) ? lds[t - d] : 0;
    __syncthreads();
    lds[t] += x;
    __syncthreads();
  }
  int excl = (t == 0) ? 0 : lds[t - 1];
  if (t == 255) partial[blockIdx.x] = lds[255];
#pragma unroll
  for (int j = 0; j < 4; ++j) {
    int i = base + t * 4 + j;
    if (i < NSEG) off[i] = excl;
    excl += v[j];
  }
}

__global__ __launch_bounds__(256) void scan_partials(int* __restrict__ partial) {
  __shared__ int lds[256];
  int t = threadIdx.x;
  int v = (t < NCHUNK) ? partial[t] : 0;
  lds[t] = v;
  __syncthreads();
  for (int d = 1; d < 256; d <<= 1) {
    int x = (t >= d) ? lds[t - d] : 0;
    __syncthreads();
    lds[t] += x;
    __syncthreads();
  }
  int excl = (t == 0) ? 0 : lds[t - 1];
  if (t < NCHUNK) partial[t] = excl;
}

__global__ __launch_bounds__(256) void scan_add(
    int* __restrict__ off, const int* __restrict__ partial,
    int* __restrict__ off_run) {
  int base = blockIdx.x * SCHUNK;
  int add = partial[blockIdx.x];
  for (int j = threadIdx.x; j < SCHUNK; j += 256) {
    int i = base + j;
    if (i < NSEG) {
      int o = off[i] + add;
      off[i] = o;
      off_run[i] = o;
    }
  }
}

// ---------------------------------------------------------------------------
// place: s_rec[pos] = (src, w) int2, pos = off_run[seg]++.
// Non-temporal store: record stream is written once, read next kernel —
// avoid L2 line allocation / cross-XCD ownership churn.
// ---------------------------------------------------------------------------
__global__ __launch_bounds__(256) void place_kernel(
    const int* __restrict__ eidx, const float* __restrict__ ew,
    int* __restrict__ off_run, int2* __restrict__ s_rec) {
  int idx = blockIdx.x * 256 + threadIdx.x;
  if (idx >= NR * NE) return;
  int r = idx / NE, e = idx - r * NE;
  int src = eidx[(size_t)r * 2 * NE + e];
  int dst = eidx[(size_t)r * 2 * NE + NE + e];
  float w = ew[(size_t)r * NE + e];
  int pos = atomicAdd(&off_run[r * NN + dst], 1);
  long long rec =
      (long long)(unsigned int)src | ((long long)__float_as_uint(w) << 32);
  __builtin_nontemporal_store(rec, reinterpret_cast<long long*>(s_rec + pos));
}

// ---------------------------------------------------------------------------
// m_kernel: M_r = F @ Wr[r] in fp16. blockIdx.y = r. 128 nodes/block
// (16 sub-iters of 8) so Wr is staged 4x less often than 32-node blocks.
// ---------------------------------------------------------------------------
__global__ __launch_bounds__(256) void m_kernel(
    const float* __restrict__ feat, const float* __restrict__ Wr,
    __half* __restrict__ M) {
  __shared__ float wlds[DD * DD];   // 64 KB
  __shared__ float flds[8][DD];     // 4 KB
  int r = blockIdx.y;
  const float* W = Wr + (size_t)r * DD * DD;
  for (int i = threadIdx.x; i < DD * DD / 4; i += 256)
    reinterpret_cast<float4*>(wlds)[i] = reinterpret_cast<const float4*>(W)[i];
  int dgrp = threadIdx.x & 31, nl = threadIdx.x >> 5;
  int nbase = blockIdx.x * 128;
  for (int s = 0; s < 16; ++s) {
    int n0 = nbase + s * 8;
    __syncthreads();
    {
      int n = n0 + nl;
      float4 fv = make_float4(0.f, 0.f, 0.f, 0.f);
      if (n < NN) fv = reinterpret_cast<const float4*>(feat + (size_t)n * DD)[dgrp];
      reinterpret_cast<float4*>(&flds[nl][0])[dgrp] = fv;
    }
    __syncthreads();
    int n = n0 + nl;
    float4 acc = make_float4(0.f, 0.f, 0.f, 0.f);
#pragma unroll 8
    for (int k = 0; k < DD; ++k) {
      float f = flds[nl][k];
      float4 wv = reinterpret_cast<const float4*>(&wlds[k * DD])[dgrp];
      acc.x += f * wv.x; acc.y += f * wv.y;
      acc.z += f * wv.z; acc.w += f * wv.w;
    }
    if (n < NN) {
      __half2 h01 = __floats2half2_rn(acc.x, acc.y);
      __half2 h23 = __floats2half2_rn(acc.z, acc.w);
      __half2* mp = reinterpret_cast<__half2*>(
          M + ((size_t)r * NN + n) * DD + 4 * dgrp);
      mp[0] = h01;
      mp[1] = h23;
    }
  }
}

// ---------------------------------------------------------------------------
// gather_y: one wave per node, zero LDS, max occupancy.
// y[n] = sum_r rw[n,r] * ( sum_e w_e * M_r[src_e] + (sum_e w_e) * br[r] )
// Records are read SEQUENTIALLY (src,w inline) — no random metadata reads.
// 8-edge batches: lanes 0..7 load records, __shfl broadcast, 8 independent
// 256B M-row loads in flight.
// ---------------------------------------------------------------------------
__global__ __launch_bounds__(256) void gather_y(
    const __half* __restrict__ M, const int2* __restrict__ s_rec,
    const int* __restrict__ off, const int* __restrict__ cnt,
    const float* __restrict__ relw, const float* __restrict__ br,
    float* __restrict__ y) {
  int wave = threadIdx.x >> 6, lane = threadIdx.x & 63;
  int n = blockIdx.x * 4 + wave;
  if (n >= NN) return;
  float4 rw4 = reinterpret_cast<const float4*>(relw)[n];
  float rwv[4] = {rw4.x, rw4.y, rw4.z, rw4.w};
  float2 acc = make_float2(0.f, 0.f);
#pragma unroll
  for (int r = 0; r < NR; ++r) {
    int seg = r * NN + n;
    int start = off[seg], deg = cnt[seg];
    const __half2* mbase =
        reinterpret_cast<const __half2*>(M + (size_t)r * NN * DD);
    float2 pacc = make_float2(0.f, 0.f);
    float sw = 0.f;
    for (int i = 0; i < deg; i += 8) {
      int nb = deg - i;
      nb = nb > 8 ? 8 : nb;
      int2 rec = make_int2(0, 0);
      if (lane < nb) rec = s_rec[start + i + lane];
      int src_l = rec.x;
      float w_l = __int_as_float(rec.y);
      if (nb == 8) {
#pragma unroll
        for (int j = 0; j < 8; ++j) {
          int s = __shfl(src_l, j);
          float w = __shfl(w_l, j);
          float2 mf = __half22float2(mbase[(size_t)s * 64 + lane]);
          pacc.x += w * mf.x;
          pacc.y += w * mf.y;
          sw += w;
        }
      } else {
        for (int j = 0; j < nb; ++j) {
          int s = __shfl(src_l, j);
          float w = __shfl(w_l, j);
          float2 mf = __half22float2(mbase[(size_t)s * 64 + lane]);
          pacc.x += w * mf.x;
          pacc.y += w * mf.y;
          sw += w;
        }
      }
    }
    float2 bv = reinterpret_cast<const float2*>(br + (size_t)r * DD)[lane];
    float rw = rwv[r];
    acc.x += rw * (pacc.x + sw * bv.x);
    acc.y += rw * (pacc.y + sw * bv.y);
  }
  reinterpret_cast<float2*>(y + (size_t)n * DD)[lane] = acc;
}

// ---------------------------------------------------------------------------
// gate: out = sigmoid(out @ Wg + bg) * out, in place (out holds y)
// ---------------------------------------------------------------------------
__global__ __launch_bounds__(256) void gate_kernel(
    float* __restrict__ out, const float* __restrict__ Wg,
    const float* __restrict__ bg) {
  __shared__ float wlds[DD * DD];
  __shared__ float clds[8][DD];
  for (int i = threadIdx.x; i < DD * DD / 4; i += 256)
    reinterpret_cast<float4*>(wlds)[i] = reinterpret_cast<const float4*>(Wg)[i];
  int dgrp = threadIdx.x & 31, nl = threadIdx.x >> 5;
  float4 bv = reinterpret_cast<const float4*>(bg)[dgrp];
  int nbase = blockIdx.x * 32;
  for (int s = 0; s < 4; ++s) {
    int n0 = nbase + s * 8;
    __syncthreads();
    {
      int n = n0 + nl;
      float4 cv = make_float4(0.f, 0.f, 0.f, 0.f);
      if (n < NN) cv = reinterpret_cast<const float4*>(out + (size_t)n * DD)[dgrp];
      reinterpret_cast<float4*>(&clds[nl][0])[dgrp] = cv;
    }
    __syncthreads();
    int n = n0 + nl;
    float4 acc = bv;
#pragma unroll 8
    for (int k = 0; k < DD; ++k) {
      float c = clds[nl][k];
      float4 wv = reinterpret_cast<const float4*>(&wlds[k * DD])[dgrp];
      acc.x += c * wv.x; acc.y += c * wv.y;
      acc.z += c * wv.z; acc.w += c * wv.w;
    }
    if (n < NN) {
      float4 cv = reinterpret_cast<float4*>(&clds[nl][0])[dgrp];
      float4 res;
      res.x = cv.x / (1.f + __expf(-acc.x));
      res.y = cv.y / (1.f + __expf(-acc.y));
      res.z = cv.z / (1.f + __expf(-acc.z));
      res.w = cv.w / (1.f + __expf(-acc.w));
      reinterpret_cast<float4*>(out + (size_t)n * DD)[dgrp] = res;
    }
  }
}

// ---------------------------------------------------------------------------
extern "C" void kernel_launch(void* const* d_in, const int* in_sizes, int n_in,
                              void* d_out, int out_size, void* d_ws,
                              size_t ws_size, hipStream_t stream) {
  const float* feat = (const float*)d_in[0];
  const int* eidx   = (const int*)d_in[1];   // [4][2][800000] int32
  const float* ew   = (const float*)d_in[2];
  const float* Wr   = (const float*)d_in[3];
  const float* br   = (const float*)d_in[4];
  const float* Wrw  = (const float*)d_in[5];
  const float* brw  = (const float*)d_in[6];
  const float* Wg   = (const float*)d_in[7];
  const float* bg   = (const float*)d_in[8];
  float* out = (float*)d_out;

  // ws layout (~80 MB): s_rec | cnt | off | offrun | part | relw | M
  char* p = (char*)d_ws;
  int2*   s_rec  = (int2*)p;   p += (size_t)NR * NE * 8;       // 25.6 MB
  int*    cnt    = (int*)p;    p += (size_t)NSEG * 4;
  int*    off    = (int*)p;    p += (size_t)NSEG * 4;
  int*    offrun = (int*)p;    p += (size_t)NSEG * 4;
  int*    part   = (int*)p;    p += 4096;
  float*  relw   = (float*)p;  p += (size_t)NN * NR * 4;
  __half* M      = (__half*)p; p += (size_t)NR * NN * DD * 2;  // 51.2 MB

  hipMemsetAsync(cnt, 0, (size_t)NSEG * 4, stream);

  relw_kernel<<<(NN + 3) / 4, 256, 0, stream>>>(feat, Wrw, brw, relw);
  count_kernel<<<(NR * NE + 255) / 256, 256, 0, stream>>>(eidx, cnt);
  scan_local<<<NCHUNK, 256, 0, stream>>>(cnt, off, part);
  scan_partials<<<1, 256, 0, stream>>>(part);
  scan_add<<<NCHUNK, 256, 0, stream>>>(off, part, offrun);
  place_kernel<<<(NR * NE + 255) / 256, 256, 0, stream>>>(eidx, ew, offrun,
                                                          s_rec);
  m_kernel<<<dim3((NN + 127) / 128, NR), 256, 0, stream>>>(feat, Wr, M);
  gather_y<<<(NN + 3) / 4, 256, 0, stream>>>(M, s_rec, off, cnt, relw, br,
                                             out);
  gate_kernel<<<(NN + 31) / 32, 256, 0, stream>>>(out, Wg, bg);
}